// Round 6
// baseline (475.743 us; speedup 1.0000x reference)
//
#include <hip/hip_runtime.h>
#include <hip/hip_cooperative_groups.h>

namespace cg = cooperative_groups;

#define NB 16
#define NM 32
#define NA 8400
#define NCC 80
#define NREG 64
#define A0 6400
#define A1 1600
#define A2 400
#define CAP 768
#define GRID 768

// acc layout: padded slots, 16 doubles (128 B) apart
// slot 0=splus_sum 1=pos_cls 2=tss 3=iou 4=dfl
#define ACC_STRIDE 16
#define ACC_SLOTS 5

// ---------- device helpers ----------

__device__ __forceinline__ void anch(int a, float& ax, float& ay, float& s, int& lvl, int& p) {
  if (a < A0)            { lvl = 0; p = a;          s = 8.f;  ax = (float)(p % 80); ay = (float)(p / 80); }
  else if (a < A0 + A1)  { lvl = 1; p = a - A0;     s = 16.f; ax = (float)(p % 40); ay = (float)(p / 40); }
  else                   { lvl = 2; p = a - A0 - A1; s = 32.f; ax = (float)(p % 20); ay = (float)(p / 20); }
}

__device__ __forceinline__ float cls_at(const float* c0, const float* c1, const float* c2,
                                        int b, int ch, int a) {
  if (a < A0)           return c0[((size_t)(b * NCC + ch)) * A0 + a];
  if (a < A0 + A1)      return c1[((size_t)(b * NCC + ch)) * A1 + (a - A0)];
  return c2[((size_t)(b * NCC + ch)) * A2 + (a - A0 - A1)];
}

__device__ __forceinline__ float reg_at(const float* r0, const float* r1, const float* r2,
                                        int b, int ch, int lvl, int p) {
  if (lvl == 0) return r0[((size_t)(b * NREG + ch)) * A0 + p];
  if (lvl == 1) return r1[((size_t)(b * NREG + ch)) * A1 + p];
  return r2[((size_t)(b * NREG + ch)) * A2 + p];
}

__device__ __forceinline__ void gtbox(const float* boxes, int b, int m,
                                      float& x1, float& y1, float& x2, float& y2, bool& valid) {
  const float* q = boxes + ((size_t)(b * NM + m)) * 4;
  float cx = q[0], cy = q[1], w = q[2], h = q[3];
  x1 = (cx - w * 0.5f) * 640.f; y1 = (cy - h * 0.5f) * 640.f;
  x2 = (cx + w * 0.5f) * 640.f; y2 = (cy + h * 0.5f) * 640.f;
  valid = (x1 + y1 + x2 + y2) > 0.f;
}

__device__ __forceinline__ float ciou_f(float b1x1, float b1y1, float b1x2, float b1y2,
                                        float b2x1, float b2y1, float b2x2, float b2y2) {
  const float eps = 1e-7f;
  float w1 = b1x2 - b1x1, h1 = b1y2 - b1y1;
  float w2 = b2x2 - b2x1, h2 = b2y2 - b2y1;
  float iw = fmaxf(fminf(b1x2, b2x2) - fmaxf(b1x1, b2x1), 0.f);
  float ih = fmaxf(fminf(b1y2, b2y2) - fmaxf(b1y1, b2y1), 0.f);
  float inter = iw * ih;
  float uni = w1 * h1 + w2 * h2 - inter + eps;
  float iou = inter / uni;
  float cw = fmaxf(b1x2, b2x2) - fminf(b1x1, b2x1);
  float ch = fmaxf(b1y2, b2y2) - fminf(b1y1, b2y1);
  float c2 = cw * cw + ch * ch + eps;
  float dx = b2x1 + b2x2 - b1x1 - b1x2;
  float dy = b2y1 + b2y2 - b1y1 - b1y2;
  float rho2 = (dx * dx + dy * dy) * 0.25f;
  float at = atanf(w2 / (h2 + eps)) - atanf(w1 / (h1 + eps));
  float v = 0.4052847345693511f * at * at;   // 4/pi^2
  float alpha = v / (v - iou + (1.0f + eps));
  return iou - (rho2 / c2 + v * alpha);
}

__device__ __forceinline__ float align_of(float sc, float o) {
  float o2 = o * o, o4 = o2 * o2;
  return sqrtf(sc) * (o2 * o4);  // sc^0.5 * o^6
}

__device__ __forceinline__ float softplus_fast(float x) {
  float e = __expf(-fabsf(x));
  return fmaxf(x, 0.f) + __logf(1.f + e);
}

// ---------- the single cooperative kernel ----------

__global__ __launch_bounds__(256, 3) void k_all(
    const float* c0, const float* c1, const float* c2,
    const float* r0, const float* r1, const float* r2,
    const float* boxes, const int* labels,
    float4* bb, float4* mls,
    int* cand_cnt, float* cand_val, int* cand_idx,
    int* fgcnt, int* msum, int* assign, float* amv,
    unsigned* pos_am, unsigned* pos_ov, double* acc, float* out) {

  cg::grid_group grid = cg::this_grid();
  const int tid = threadIdx.x;
  const int blk = blockIdx.x;
  const int nb = gridDim.x;
  const int nthr = nb * 256;
  const int lane = tid & 63;
  const int wid = tid >> 6;

  __shared__ float sv[CAP];
  __shared__ int   si[CAP];
  __shared__ float swv[4];
  __shared__ int   swi[4];
  __shared__ int   scnt[4];
  __shared__ double sred[256];

  // ---------------- Phase A: zero scratch + DFL decode ----------------
  for (int t = blk * 256 + tid; t < NB * NA; t += nthr) {
    fgcnt[t] = 0; msum[t] = 0;
    if (t < NB * NM) { cand_cnt[t] = 0; pos_am[t] = 0u; pos_ov[t] = 0u; }
    if (t < ACC_SLOTS * ACC_STRIDE) acc[t] = 0.0;

    int b = t / NA, a = t % NA;
    float ax, ay, s; int lvl, p;
    anch(a, ax, ay, s, lvl, p);
    const float* rg; int HW;
    if (lvl == 0) { rg = r0; HW = A0; }
    else if (lvl == 1) { rg = r1; HW = A1; }
    else { rg = r2; HW = A2; }
    const float* base = rg + ((size_t)b * NREG) * HW + p;
    float dist[4], ml[4];
    for (int sd = 0; sd < 4; ++sd) {
      float x[16]; float mx = -1e30f;
      for (int r = 0; r < 16; ++r) { x[r] = base[(size_t)(sd * 16 + r) * HW]; mx = fmaxf(mx, x[r]); }
      float se = 0.f, wsum = 0.f;
      for (int r = 0; r < 16; ++r) { float e = __expf(x[r] - mx); se += e; wsum += e * (float)r; }
      dist[sd] = wsum / se;
      ml[sd] = mx + __logf(se);
    }
    bb[t]  = make_float4(ax - dist[0], ay - dist[1], ax + dist[2], ay + dist[3]);
    mls[t] = make_float4(ml[0], ml[1], ml[2], ml[3]);
  }
  grid.sync();

  // ---------------- Phase B: candidate build (block per bm, rect scan) ----------------
  for (int bm = blk; bm < NB * NM; bm += nb) {
    int b = bm / NM, m = bm % NM;
    float gx1, gy1, gx2, gy2; bool valid;
    gtbox(boxes, b, m, gx1, gy1, gx2, gy2, valid);
    if (!valid) continue;   // uniform per block
    int lbl = labels[bm]; if (lbl < 0) lbl = 0; if (lbl >= NCC) lbl = NCC - 1;

    const int   Ws[3]   = {80, 40, 20};
    const float ss[3]   = {8.f, 16.f, 32.f};
    const int   loff[3] = {0, A0, A0 + A1};
    int rx0[3], ry0[3], rw[3], rh[3], bc[3];
    int total = 0;
    for (int l = 0; l < 3; ++l) {
      float s = ss[l]; int W = Ws[l];
      // exact range (floor(v)+1 .. ceil(u)-1) expanded by +/-1 margin; exact mask re-test inside
      int ax0 = (int)floorf((gx1 + 1e-9f) / s);          // (+1 margin folded)
      int ax1 = (int)ceilf((gx2 - 1e-9f) / s);
      int ay0 = (int)floorf((gy1 + 1e-9f) / s);
      int ay1 = (int)ceilf((gy2 - 1e-9f) / s);
      ax0 = max(ax0, 0); ay0 = max(ay0, 0);
      ax1 = min(ax1, W - 1); ay1 = min(ay1, W - 1);
      rx0[l] = ax0; ry0[l] = ay0;
      rw[l] = max(0, ax1 - ax0 + 1);
      rh[l] = max(0, ay1 - ay0 + 1);
      bc[l] = total;
      total += rw[l] * rh[l];
    }
    int iters = (total + 255) >> 8;
    for (int it = 0; it < iters; ++it) {
      int idx = it * 256 + tid;
      bool pred = false; float am = 0.f; int a = 0;
      if (idx < total) {
        int l = (idx >= bc[2]) ? 2 : ((idx >= bc[1]) ? 1 : 0);
        int r = idx - bc[l];
        int iy = r / rw[l], ix = r - iy * rw[l];
        int axg = rx0[l] + ix, ayg = ry0[l] + iy;
        a = loff[l] + ayg * Ws[l] + axg;
        float s = ss[l];
        float axp = (float)axg * s, ayp = (float)ayg * s;
        float mn = fminf(fminf(axp - gx1, ayp - gy1), fminf(gx2 - axp, gy2 - ayp));
        if (mn > 1e-9f) {
          pred = true;
          float4 pb = bb[(size_t)b * NA + a];
          float c = ciou_f(gx1, gy1, gx2, gy2, pb.x * s, pb.y * s, pb.z * s, pb.w * s);
          float o = fmaxf(c, 0.f);
          float x = cls_at(c0, c1, c2, b, lbl, a);
          float sc = 1.f / (1.f + expf(-x));
          am = align_of(sc, o);
        }
      }
      unsigned long long mask = __ballot(pred);
      if (mask) {
        int nact = __popcll(mask);
        int leader = __ffsll(mask) - 1;
        int basec = 0;
        if (lane == leader) basec = atomicAdd(&cand_cnt[bm], nact);
        basec = __shfl(basec, leader);
        if (pred) {
          int off = basec + __popcll(mask & ((1ull << lane) - 1ull));
          if (off < CAP) { cand_val[(size_t)bm * CAP + off] = am; cand_idx[(size_t)bm * CAP + off] = a; }
        }
      }
    }
  }
  grid.sync();

  // ---------------- Phase C: top-10 per bm (exact lax.top_k ties) ----------------
  for (int bm = blk; bm < NB * NM; bm += nb) {
    int b = bm / NM, m = bm % NM;
    int n = cand_cnt[bm]; if (n > CAP) n = CAP;
    if (n == 0) continue;   // uniform per block
    for (int j = tid; j < n; j += 256) {
      sv[j] = cand_val[(size_t)bm * CAP + j];
      si[j] = cand_idx[(size_t)bm * CAP + j];
    }
    __syncthreads();
    // count positives
    int cnt = 0;
    for (int j = tid; j < n; j += 256) if (sv[j] > 0.f) cnt++;
    for (int o = 32; o; o >>= 1) cnt += __shfl_xor(cnt, o);
    if (lane == 0) scnt[wid] = cnt;
    __syncthreads();
    if (tid == 0) scnt[0] = scnt[0] + scnt[1] + scnt[2] + scnt[3];
    __syncthreads();
    int npos = scnt[0];
    __syncthreads();

    if (npos > 10) {
      for (int k = 0; k < 10; ++k) {
        float bv = -1.f; int bi = 1 << 30;
        for (int j = tid; j < n; j += 256) {
          float v = sv[j]; int ix = si[j];
          if (v > bv || (v == bv && ix < bi)) { bv = v; bi = ix; }
        }
        for (int o = 32; o; o >>= 1) {
          float v = __shfl_xor(bv, o); int ix = __shfl_xor(bi, o);
          if (v > bv || (v == bv && ix < bi)) { bv = v; bi = ix; }
        }
        if (lane == 0) { swv[wid] = bv; swi[wid] = bi; }
        __syncthreads();
        if (tid == 0) {
          float v = swv[0]; int i = swi[0];
          for (int w = 1; w < 4; ++w)
            if (swv[w] > v || (swv[w] == v && swi[w] < i)) { v = swv[w]; i = swi[w]; }
          swv[0] = v; swi[0] = i;
        }
        __syncthreads();
        bi = swi[0];
        for (int j = tid; j < n; j += 256) if (si[j] == bi) sv[j] = -1.f;
        if (tid == 0) {
          atomicAdd(&fgcnt[(size_t)b * NA + bi], 1);
          atomicAdd(&msum[(size_t)b * NA + bi], m);
        }
        __syncthreads();
      }
    } else {
      for (int j = tid; j < n; j += 256) {
        if (sv[j] > 0.f) {
          atomicAdd(&fgcnt[(size_t)b * NA + si[j]], 1);
          atomicAdd(&msum[(size_t)b * NA + si[j]], m);
        }
      }
      // zero-tie fill (requires anchor index < 10 — rare corner)
      int need = 10 - npos;
      for (int j = tid; j < n; j += 256) {
        if (sv[j] == 0.f) {
          int i = si[j];
          if (i < 10) {
            int pb = 0;
            for (int q = 0; q < n; ++q) pb += (sv[q] > 0.f && si[q] < i) ? 1 : 0;
            if (i - pb < need) {
              atomicAdd(&fgcnt[(size_t)b * NA + i], 1);
              atomicAdd(&msum[(size_t)b * NA + i], m);
            }
          }
        }
      }
    }
    __syncthreads();
  }
  grid.sync();

  // ---------------- Phase D: resolve + per-gt maxima ----------------
  for (int t = blk * 256 + tid; t < NB * NA; t += nthr) {
    int b = t / NA, a = t % NA;
    int fg = fgcnt[t];
    int asn = -1; float o = 0.f;
    if (fg > 0) {
      float ax, ay, s; int lvl, p;
      anch(a, ax, ay, s, lvl, p);
      float axp = ax * s, ayp = ay * s;
      float4 pb = bb[t];
      float px1 = pb.x * s, py1 = pb.y * s, px2 = pb.z * s, py2 = pb.w * s;
      if (fg == 1) {
        asn = msum[t];
        float gx1, gy1, gx2, gy2; bool valid;
        gtbox(boxes, b, asn, gx1, gy1, gx2, gy2, valid);
        o = fmaxf(ciou_f(gx1, gy1, gx2, gy2, px1, py1, px2, py2), 0.f);
      } else {
        float bv = -1e30f; int bi = 0;
        for (int m = 0; m < NM; ++m) {
          float gx1, gy1, gx2, gy2; bool valid;
          gtbox(boxes, b, m, gx1, gy1, gx2, gy2, valid);
          float om = 0.f;
          if (valid) {
            float mn = fminf(fminf(axp - gx1, ayp - gy1), fminf(gx2 - axp, gy2 - ayp));
            if (mn > 1e-9f)
              om = fmaxf(ciou_f(gx1, gy1, gx2, gy2, px1, py1, px2, py2), 0.f);
          }
          if (om > bv) { bv = om; bi = m; }
        }
        asn = bi; o = bv;
      }
      float am = 0.f;
      if (o > 0.f) {
        int lbl = labels[b * NM + asn]; if (lbl < 0) lbl = 0; if (lbl >= NCC) lbl = NCC - 1;
        float x = cls_at(c0, c1, c2, b, lbl, a);
        float sc = 1.f / (1.f + expf(-x));
        am = align_of(sc, o);
        atomicMax(&pos_am[b * NM + asn], __float_as_uint(am));
        atomicMax(&pos_ov[b * NM + asn], __float_as_uint(o));
      }
      amv[t] = am;
    }
    assign[t] = asn;
  }
  grid.sync();

  // ---------------- Phase E: pos losses + BCE softplus sum ----------------
  {
    double t_norm = 0.0, t_x = 0.0, t_iou = 0.0, t_dfl = 0.0;
    for (int t = blk * 256 + tid; t < NB * NA; t += nthr) {
      int asn = assign[t]; if (asn < 0) continue;
      int b = t / NA, a = t % NA;
      float pam = __uint_as_float(pos_am[b * NM + asn]);
      float pov = __uint_as_float(pos_ov[b * NM + asn]);
      float norm = amv[t] * pov / (pam + 1e-9f);
      int lbl = labels[b * NM + asn]; if (lbl < 0) lbl = 0; if (lbl >= NCC) lbl = NCC - 1;
      float x = cls_at(c0, c1, c2, b, lbl, a);
      float gx1, gy1, gx2, gy2; bool valid;
      gtbox(boxes, b, asn, gx1, gy1, gx2, gy2, valid);
      float ax, ay, s; int lvl, p;
      anch(a, ax, ay, s, lvl, p);
      float inv_s = 1.f / s;
      float tx1 = gx1 * inv_s, ty1 = gy1 * inv_s, tx2 = gx2 * inv_s, ty2 = gy2 * inv_s;
      float4 pb = bb[t];
      float iou = ciou_f(pb.x, pb.y, pb.z, pb.w, tx1, ty1, tx2, ty2);
      float4 ml = mls[t];
      float tgt[4] = { ax - tx1, ay - ty1, tx2 - ax, ty2 - ay };
      float mlv[4] = { ml.x, ml.y, ml.z, ml.w };
      float dfl = 0.f;
      for (int sd = 0; sd < 4; ++sd) {
        float tv = fminf(fmaxf(tgt[sd], 0.f), 14.99f);
        float tlf = floorf(tv);
        int tl = (int)tlf;
        float wl = (tlf + 1.f) - tv;
        float xtl = reg_at(r0, r1, r2, b, sd * 16 + tl,     lvl, p);
        float xtr = reg_at(r0, r1, r2, b, sd * 16 + tl + 1, lvl, p);
        dfl += -((xtl - mlv[sd]) * wl + (xtr - mlv[sd]) * (1.f - wl));
      }
      dfl *= 0.25f;
      t_norm += (double)norm;
      t_x    += (double)(norm * x);
      t_iou  += (double)((1.f - iou) * norm);
      t_dfl  += (double)(dfl * norm);
    }
    double vals[4] = { t_norm, t_x, t_iou, t_dfl };
    const int slots[4] = { 2, 1, 3, 4 };
    for (int q = 0; q < 4; ++q) {
      sred[tid] = vals[q];
      __syncthreads();
      for (int off = 128; off; off >>= 1) {
        if (tid < off) sred[tid] += sred[tid + off];
        __syncthreads();
      }
      if (tid == 0 && sred[0] != 0.0) atomicAdd(&acc[slots[q] * ACC_STRIDE], sred[0]);
      __syncthreads();
    }

    // BCE softplus sum over all class logits (float4)
    const size_t N0 = (size_t)NB * NCC * A0 / 4;
    const size_t N1 = (size_t)NB * NCC * A1 / 4;
    const size_t N2 = (size_t)NB * NCC * A2 / 4;
    const size_t NT = N0 + N1 + N2;
    const float4* f0 = (const float4*)c0;
    const float4* f1 = (const float4*)c1;
    const float4* f2 = (const float4*)c2;
    float s0 = 0.f, s1 = 0.f;
    for (size_t i = (size_t)blk * 256 + tid; i < NT; i += (size_t)nthr) {
      float4 v;
      if (i < N0) v = f0[i];
      else if (i < N0 + N1) v = f1[i - N0];
      else v = f2[i - N0 - N1];
      s0 += softplus_fast(v.x) + softplus_fast(v.z);
      s1 += softplus_fast(v.y) + softplus_fast(v.w);
    }
    sred[tid] = (double)(s0 + s1);
    __syncthreads();
    for (int off = 128; off; off >>= 1) {
      if (tid < off) sred[tid] += sred[tid + off];
      __syncthreads();
    }
    if (tid == 0) atomicAdd(&acc[0], sred[0]);
  }
  grid.sync();

  // ---------------- Phase F: compose outputs ----------------
  if (blk == 0 && tid == 0) {
    double a0 = atomicAdd(&acc[0], 0.0);
    double a1 = atomicAdd(&acc[1 * ACC_STRIDE], 0.0);
    double a2 = atomicAdd(&acc[2 * ACC_STRIDE], 0.0);
    double a3 = atomicAdd(&acc[3 * ACC_STRIDE], 0.0);
    double a4 = atomicAdd(&acc[4 * ACC_STRIDE], 0.0);
    double tss = a2; if (tss < 1.0) tss = 1.0;
    double l0 = 0.5 * (a0 - a1) / tss;
    double l1 = 7.5 * a3 / tss;
    double l2 = 1.5 * a4 / tss;
    out[0] = (float)(l0 + l1 + l2);
    out[1] = (float)l0;
    out[2] = (float)l1;
    out[3] = (float)l2;
  }
}

// ---------- launch ----------

extern "C" void kernel_launch(void* const* d_in, const int* in_sizes, int n_in,
                              void* d_out, int out_size, void* d_ws, size_t ws_size,
                              hipStream_t stream) {
  (void)in_sizes; (void)n_in; (void)out_size; (void)ws_size;
  const float* cls0  = (const float*)d_in[0];
  const float* cls1  = (const float*)d_in[1];
  const float* cls2  = (const float*)d_in[2];
  const float* reg0  = (const float*)d_in[3];
  const float* reg1  = (const float*)d_in[4];
  const float* reg2  = (const float*)d_in[5];
  const float* boxes = (const float*)d_in[6];
  const int*   labels = (const int*)d_in[7];
  float* out = (float*)d_out;

  const size_t BA = (size_t)NB * NA;  // 134400
  const int    BM = NB * NM;          // 512

  char* wsb = (char*)d_ws;
  double*   acc      = (double*)wsb;                       // ACC_SLOTS*ACC_STRIDE doubles
  unsigned* pos_am   = (unsigned*)(acc + ACC_SLOTS * ACC_STRIDE); // BM
  unsigned* pos_ov   = pos_am + BM;                        // BM
  int*      cand_cnt = (int*)(pos_ov + BM);                // BM
  int*      fgcnt    = cand_cnt + BM;                      // BA
  int*      msum     = fgcnt + BA;                         // BA
  float*    bbp      = (float*)(msum + BA);                // BA*4
  float*    mlsp     = bbp + BA * 4;                       // BA*4
  float*    amv      = mlsp + BA * 4;                      // BA
  int*      assign   = (int*)(amv + BA);                   // BA
  float*    cand_val = (float*)(assign + BA);              // BM*CAP
  int*      cand_idx = (int*)(cand_val + (size_t)BM * CAP);// BM*CAP

  float4* bb  = (float4*)bbp;
  float4* mls = (float4*)mlsp;

  void* args[] = {
    (void*)&cls0, (void*)&cls1, (void*)&cls2,
    (void*)&reg0, (void*)&reg1, (void*)&reg2,
    (void*)&boxes, (void*)&labels,
    (void*)&bb, (void*)&mls,
    (void*)&cand_cnt, (void*)&cand_val, (void*)&cand_idx,
    (void*)&fgcnt, (void*)&msum, (void*)&assign, (void*)&amv,
    (void*)&pos_am, (void*)&pos_ov, (void*)&acc, (void*)&out
  };
  hipLaunchCooperativeKernel((void*)k_all, dim3(GRID), dim3(256), args, 0, stream);
}

// Round 7
// 100.281 us; speedup vs baseline: 4.7441x; 4.7441x over previous
//
#include <hip/hip_runtime.h>

#define NB 16
#define NM 32
#define NA 8400
#define NCC 80
#define NREG 64
#define A0 6400
#define A1 1600
#define A2 400
#define CAP 768

#define PRE_GRID 1024
#define PL_GRID 525   // 525*256 == NB*NA

// ---------- device helpers ----------

__device__ __forceinline__ void anch(int a, float& ax, float& ay, float& s, int& lvl, int& p) {
  if (a < A0)            { lvl = 0; p = a;          s = 8.f;  ax = (float)(p % 80); ay = (float)(p / 80); }
  else if (a < A0 + A1)  { lvl = 1; p = a - A0;     s = 16.f; ax = (float)(p % 40); ay = (float)(p / 40); }
  else                   { lvl = 2; p = a - A0 - A1; s = 32.f; ax = (float)(p % 20); ay = (float)(p / 20); }
}

__device__ __forceinline__ float cls_at(const float* c0, const float* c1, const float* c2,
                                        int b, int ch, int a) {
  if (a < A0)           return c0[((size_t)(b * NCC + ch)) * A0 + a];
  if (a < A0 + A1)      return c1[((size_t)(b * NCC + ch)) * A1 + (a - A0)];
  return c2[((size_t)(b * NCC + ch)) * A2 + (a - A0 - A1)];
}

__device__ __forceinline__ float reg_at(const float* r0, const float* r1, const float* r2,
                                        int b, int ch, int lvl, int p) {
  if (lvl == 0) return r0[((size_t)(b * NREG + ch)) * A0 + p];
  if (lvl == 1) return r1[((size_t)(b * NREG + ch)) * A1 + p];
  return r2[((size_t)(b * NREG + ch)) * A2 + p];
}

__device__ __forceinline__ void gtbox(const float* boxes, int b, int m,
                                      float& x1, float& y1, float& x2, float& y2, bool& valid) {
  const float* q = boxes + ((size_t)(b * NM + m)) * 4;
  float cx = q[0], cy = q[1], w = q[2], h = q[3];
  x1 = (cx - w * 0.5f) * 640.f; y1 = (cy - h * 0.5f) * 640.f;
  x2 = (cx + w * 0.5f) * 640.f; y2 = (cy + h * 0.5f) * 640.f;
  valid = (x1 + y1 + x2 + y2) > 0.f;
}

__device__ __forceinline__ float ciou_f(float b1x1, float b1y1, float b1x2, float b1y2,
                                        float b2x1, float b2y1, float b2x2, float b2y2) {
  const float eps = 1e-7f;
  float w1 = b1x2 - b1x1, h1 = b1y2 - b1y1;
  float w2 = b2x2 - b2x1, h2 = b2y2 - b2y1;
  float iw = fmaxf(fminf(b1x2, b2x2) - fmaxf(b1x1, b2x1), 0.f);
  float ih = fmaxf(fminf(b1y2, b2y2) - fmaxf(b1y1, b2y1), 0.f);
  float inter = iw * ih;
  float uni = w1 * h1 + w2 * h2 - inter + eps;
  float iou = inter / uni;
  float cw = fmaxf(b1x2, b2x2) - fminf(b1x1, b2x1);
  float ch = fmaxf(b1y2, b2y2) - fminf(b1y1, b2y1);
  float c2 = cw * cw + ch * ch + eps;
  float dx = b2x1 + b2x2 - b1x1 - b1x2;
  float dy = b2y1 + b2y2 - b1y1 - b1y2;
  float rho2 = (dx * dx + dy * dy) * 0.25f;
  float at = atanf(w2 / (h2 + eps)) - atanf(w1 / (h1 + eps));
  float v = 0.4052847345693511f * at * at;   // 4/pi^2
  float alpha = v / (v - iou + (1.0f + eps));
  return iou - (rho2 / c2 + v * alpha);
}

__device__ __forceinline__ float align_of(float sc, float o) {
  float o2 = o * o, o4 = o2 * o2;
  return sqrtf(sc) * (o2 * o4);  // sc^0.5 * o^6
}

__device__ __forceinline__ float softplus_fast(float x) {
  float e = __expf(-fabsf(x));
  return fmaxf(x, 0.f) + __logf(1.f + e);
}

// ---------- kernel 1: zero scratch + DFL decode + BCE softplus partials ----------

__global__ __launch_bounds__(256) void k_pre(
    const float* r0, const float* r1, const float* r2,
    const float* c0, const float* c1, const float* c2,
    float4* bb, float4* mls, int* fgcnt, int* msum,
    unsigned* pos_am, unsigned* pos_ov, int* done_ctr, double* bce_part) {
  const int gtid = blockIdx.x * 256 + threadIdx.x;
  const int nthr = gridDim.x * 256;
  if (gtid == 0) *done_ctr = 0;

  for (int t = gtid; t < NB * NA; t += nthr) {
    fgcnt[t] = 0; msum[t] = 0;
    if (t < NB * NM) { pos_am[t] = 0u; pos_ov[t] = 0u; }

    int b = t / NA, a = t % NA;
    float ax, ay, s; int lvl, p;
    anch(a, ax, ay, s, lvl, p);
    const float* rg; int HW;
    if (lvl == 0) { rg = r0; HW = A0; }
    else if (lvl == 1) { rg = r1; HW = A1; }
    else { rg = r2; HW = A2; }
    const float* base = rg + ((size_t)b * NREG) * HW + p;
    float dist[4], ml[4];
    for (int sd = 0; sd < 4; ++sd) {
      float x[16]; float mx = -1e30f;
      for (int r = 0; r < 16; ++r) { x[r] = base[(size_t)(sd * 16 + r) * HW]; mx = fmaxf(mx, x[r]); }
      float se = 0.f, wsum = 0.f;
      for (int r = 0; r < 16; ++r) { float e = __expf(x[r] - mx); se += e; wsum += e * (float)r; }
      dist[sd] = wsum / se;
      ml[sd] = mx + __logf(se);
    }
    bb[t]  = make_float4(ax - dist[0], ay - dist[1], ax + dist[2], ay + dist[3]);
    mls[t] = make_float4(ml[0], ml[1], ml[2], ml[3]);
  }

  // BCE softplus over all class logits (float4)
  const size_t N0 = (size_t)NB * NCC * A0 / 4;
  const size_t N1 = (size_t)NB * NCC * A1 / 4;
  const size_t N2 = (size_t)NB * NCC * A2 / 4;
  const size_t NT = N0 + N1 + N2;
  const float4* f0 = (const float4*)c0;
  const float4* f1 = (const float4*)c1;
  const float4* f2 = (const float4*)c2;
  float s0 = 0.f, s1 = 0.f;
  for (size_t i = (size_t)gtid; i < NT; i += (size_t)nthr) {
    float4 v;
    if (i < N0) v = f0[i];
    else if (i < N0 + N1) v = f1[i - N0];
    else v = f2[i - N0 - N1];
    s0 += softplus_fast(v.x) + softplus_fast(v.z);
    s1 += softplus_fast(v.y) + softplus_fast(v.w);
  }
  __shared__ double sred[256];
  sred[threadIdx.x] = (double)(s0 + s1);
  __syncthreads();
  for (int off = 128; off; off >>= 1) {
    if (threadIdx.x < off) sred[threadIdx.x] += sred[threadIdx.x + off];
    __syncthreads();
  }
  if (threadIdx.x == 0) bce_part[blockIdx.x] = sred[0];  // plain store, no zero needed
}

// ---------- kernel 2: rect-scan candidates + in-block top-10 (exact lax.top_k ties) ----------

__global__ __launch_bounds__(256) void k_assign(
    const float* boxes, const int* labels, const float4* bb,
    const float* c0, const float* c1, const float* c2,
    int* fgcnt, int* msum) {
  __shared__ float sv[CAP];
  __shared__ int   si[CAP];
  __shared__ int   s_n;
  __shared__ float swv[4];
  __shared__ int   swi[4];
  __shared__ int   scnt[4];
  const int bm = blockIdx.x;
  const int b = bm / NM, m = bm % NM;
  const int tid = threadIdx.x;
  const int lane = tid & 63;
  const int wid = tid >> 6;

  float gx1, gy1, gx2, gy2; bool valid;
  gtbox(boxes, b, m, gx1, gy1, gx2, gy2, valid);
  if (!valid) return;   // uniform per block
  int lbl = labels[bm]; if (lbl < 0) lbl = 0; if (lbl >= NCC) lbl = NCC - 1;
  if (tid == 0) s_n = 0;
  __syncthreads();

  const int   Ws[3]   = {80, 40, 20};
  const float ss[3]   = {8.f, 16.f, 32.f};
  const int   loff[3] = {0, A0, A0 + A1};
  int rx0[3], ry0[3], rw[3], bc[3];
  int total = 0;
  for (int l = 0; l < 3; ++l) {
    float s = ss[l]; int W = Ws[l];
    int ax0 = (int)floorf((gx1 + 1e-9f) / s);
    int ax1 = (int)ceilf((gx2 - 1e-9f) / s);
    int ay0 = (int)floorf((gy1 + 1e-9f) / s);
    int ay1 = (int)ceilf((gy2 - 1e-9f) / s);
    ax0 = max(ax0, 0); ay0 = max(ay0, 0);
    ax1 = min(ax1, W - 1); ay1 = min(ay1, W - 1);
    rx0[l] = ax0; ry0[l] = ay0;
    rw[l] = max(0, ax1 - ax0 + 1);
    int rhl = max(0, ay1 - ay0 + 1);
    bc[l] = total;
    total += rw[l] * rhl;
  }
  int iters = (total + 255) >> 8;
  for (int it = 0; it < iters; ++it) {
    int idx = it * 256 + tid;
    bool pred = false; float am = 0.f; int a = 0;
    if (idx < total) {
      int l = (idx >= bc[2]) ? 2 : ((idx >= bc[1]) ? 1 : 0);
      int r = idx - bc[l];
      int iy = r / rw[l], ix = r - iy * rw[l];
      int axg = rx0[l] + ix, ayg = ry0[l] + iy;
      a = loff[l] + ayg * Ws[l] + axg;
      float s = ss[l];
      float axp = (float)axg * s, ayp = (float)ayg * s;
      float mn = fminf(fminf(axp - gx1, ayp - gy1), fminf(gx2 - axp, gy2 - ayp));
      if (mn > 1e-9f) {
        pred = true;
        float4 pb = bb[(size_t)b * NA + a];
        float c = ciou_f(gx1, gy1, gx2, gy2, pb.x * s, pb.y * s, pb.z * s, pb.w * s);
        float o = fmaxf(c, 0.f);
        float x = cls_at(c0, c1, c2, b, lbl, a);
        float sc = 1.f / (1.f + expf(-x));
        am = align_of(sc, o);
      }
    }
    unsigned long long mask = __ballot(pred);
    if (mask) {
      int nact = __popcll(mask);
      int leader = __ffsll(mask) - 1;
      int basec = 0;
      if (lane == leader) basec = atomicAdd(&s_n, nact);
      basec = __shfl(basec, leader);
      if (pred) {
        int off = basec + __popcll(mask & ((1ull << lane) - 1ull));
        if (off < CAP) { sv[off] = am; si[off] = a; }
      }
    }
  }
  __syncthreads();
  int n = s_n; if (n > CAP) n = CAP;
  if (n == 0) return;

  // count positives
  int cnt = 0;
  for (int j = tid; j < n; j += 256) if (sv[j] > 0.f) cnt++;
  for (int o = 32; o; o >>= 1) cnt += __shfl_xor(cnt, o);
  if (lane == 0) scnt[wid] = cnt;
  __syncthreads();
  if (tid == 0) scnt[0] = scnt[0] + scnt[1] + scnt[2] + scnt[3];
  __syncthreads();
  int npos = scnt[0];
  __syncthreads();

  if (npos > 10) {
    for (int k = 0; k < 10; ++k) {
      float bv = -1.f; int bi = 1 << 30;
      for (int j = tid; j < n; j += 256) {
        float v = sv[j]; int ix = si[j];
        if (v > bv || (v == bv && ix < bi)) { bv = v; bi = ix; }
      }
      for (int o = 32; o; o >>= 1) {
        float v = __shfl_xor(bv, o); int ix = __shfl_xor(bi, o);
        if (v > bv || (v == bv && ix < bi)) { bv = v; bi = ix; }
      }
      if (lane == 0) { swv[wid] = bv; swi[wid] = bi; }
      __syncthreads();
      if (tid == 0) {
        float v = swv[0]; int i = swi[0];
        for (int w = 1; w < 4; ++w)
          if (swv[w] > v || (swv[w] == v && swi[w] < i)) { v = swv[w]; i = swi[w]; }
        swi[0] = i;
      }
      __syncthreads();
      bi = swi[0];
      for (int j = tid; j < n; j += 256) if (si[j] == bi) sv[j] = -1.f;
      if (tid == 0) {
        atomicAdd(&fgcnt[(size_t)b * NA + bi], 1);
        atomicAdd(&msum[(size_t)b * NA + bi], m);
      }
      __syncthreads();
    }
  } else {
    for (int j = tid; j < n; j += 256) {
      if (sv[j] > 0.f) {
        atomicAdd(&fgcnt[(size_t)b * NA + si[j]], 1);
        atomicAdd(&msum[(size_t)b * NA + si[j]], m);
      }
    }
    // zero-tie fill (anchor index < 10 — rare corner)
    int need = 10 - npos;
    for (int j = tid; j < n; j += 256) {
      if (sv[j] == 0.f) {
        int i = si[j];
        if (i < 10) {
          int pb = 0;
          for (int q = 0; q < n; ++q) pb += (sv[q] > 0.f && si[q] < i) ? 1 : 0;
          if (i - pb < need) {
            atomicAdd(&fgcnt[(size_t)b * NA + i], 1);
            atomicAdd(&msum[(size_t)b * NA + i], m);
          }
        }
      }
    }
  }
}

// ---------- kernel 3: resolve assignment + per-gt maxima ----------

__global__ __launch_bounds__(256) void k_resolve(const float* boxes, const int* labels,
                                                 const float4* bb,
                                                 const float* c0, const float* c1, const float* c2,
                                                 const int* fgcnt, const int* msum,
                                                 int* assign, float* amv,
                                                 unsigned* pos_am, unsigned* pos_ov) {
  int t = blockIdx.x * blockDim.x + threadIdx.x;
  if (t >= NB * NA) return;
  int b = t / NA, a = t % NA;
  int fg = fgcnt[t];
  int asn = -1; float o = 0.f;
  if (fg > 0) {
    float ax, ay, s; int lvl, p;
    anch(a, ax, ay, s, lvl, p);
    float axp = ax * s, ayp = ay * s;
    float4 pb = bb[t];
    float px1 = pb.x * s, py1 = pb.y * s, px2 = pb.z * s, py2 = pb.w * s;
    if (fg == 1) {
      asn = msum[t];
      float gx1, gy1, gx2, gy2; bool valid;
      gtbox(boxes, b, asn, gx1, gy1, gx2, gy2, valid);
      o = fmaxf(ciou_f(gx1, gy1, gx2, gy2, px1, py1, px2, py2), 0.f);
    } else {
      float bv = -1e30f; int bi = 0;
      for (int m = 0; m < NM; ++m) {
        float gx1, gy1, gx2, gy2; bool valid;
        gtbox(boxes, b, m, gx1, gy1, gx2, gy2, valid);
        float om = 0.f;
        if (valid) {
          float mn = fminf(fminf(axp - gx1, ayp - gy1), fminf(gx2 - axp, gy2 - ayp));
          if (mn > 1e-9f)
            om = fmaxf(ciou_f(gx1, gy1, gx2, gy2, px1, py1, px2, py2), 0.f);
        }
        if (om > bv) { bv = om; bi = m; }
      }
      asn = bi; o = bv;
    }
    float am = 0.f;
    if (o > 0.f) {
      int lbl = labels[b * NM + asn]; if (lbl < 0) lbl = 0; if (lbl >= NCC) lbl = NCC - 1;
      float x = cls_at(c0, c1, c2, b, lbl, a);
      float sc = 1.f / (1.f + expf(-x));
      am = align_of(sc, o);
      atomicMax(&pos_am[b * NM + asn], __float_as_uint(am));
      atomicMax(&pos_ov[b * NM + asn], __float_as_uint(o));
    }
    amv[t] = am;
  }
  assign[t] = asn;
}

// ---------- kernel 4: pos losses (block partials) + last-block final compose ----------

__global__ __launch_bounds__(256) void k_post(const float* c0, const float* c1, const float* c2,
    const float* r0, const float* r1, const float* r2,
    const float* boxes, const int* labels, const int* assign, const float* amv,
    const float4* bb, const float4* mls, const unsigned* pos_am, const unsigned* pos_ov,
    double* pl_part, double* bce_part, int* done_ctr, float* out) {
  const int tid = threadIdx.x;
  const int t = blockIdx.x * 256 + tid;
  double t_norm = 0.0, t_x = 0.0, t_iou = 0.0, t_dfl = 0.0;
  int asn = (t < NB * NA) ? assign[t] : -1;
  if (asn >= 0) {
    int b = t / NA, a = t % NA;
    float pam = __uint_as_float(pos_am[b * NM + asn]);
    float pov = __uint_as_float(pos_ov[b * NM + asn]);
    float norm = amv[t] * pov / (pam + 1e-9f);
    int lbl = labels[b * NM + asn]; if (lbl < 0) lbl = 0; if (lbl >= NCC) lbl = NCC - 1;
    float x = cls_at(c0, c1, c2, b, lbl, a);
    float gx1, gy1, gx2, gy2; bool valid;
    gtbox(boxes, b, asn, gx1, gy1, gx2, gy2, valid);
    float ax, ay, s; int lvl, p;
    anch(a, ax, ay, s, lvl, p);
    float inv_s = 1.f / s;
    float tx1 = gx1 * inv_s, ty1 = gy1 * inv_s, tx2 = gx2 * inv_s, ty2 = gy2 * inv_s;
    float4 pb = bb[t];
    float iou = ciou_f(pb.x, pb.y, pb.z, pb.w, tx1, ty1, tx2, ty2);
    float4 ml = mls[t];
    float tgt[4] = { ax - tx1, ay - ty1, tx2 - ax, ty2 - ay };
    float mlv[4] = { ml.x, ml.y, ml.z, ml.w };
    float dfl = 0.f;
    for (int sd = 0; sd < 4; ++sd) {
      float tv = fminf(fmaxf(tgt[sd], 0.f), 14.99f);
      float tlf = floorf(tv);
      int tl = (int)tlf;
      float wl = (tlf + 1.f) - tv;
      float xtl = reg_at(r0, r1, r2, b, sd * 16 + tl,     lvl, p);
      float xtr = reg_at(r0, r1, r2, b, sd * 16 + tl + 1, lvl, p);
      dfl += -((xtl - mlv[sd]) * wl + (xtr - mlv[sd]) * (1.f - wl));
    }
    dfl *= 0.25f;
    t_norm = (double)norm;
    t_x    = (double)(norm * x);
    t_iou  = (double)((1.f - iou) * norm);
    t_dfl  = (double)(dfl * norm);
  }
  __shared__ double sred[256];
  double vals[4] = { t_norm, t_x, t_iou, t_dfl };
  for (int q = 0; q < 4; ++q) {
    sred[tid] = vals[q];
    __syncthreads();
    for (int off = 128; off; off >>= 1) {
      if (tid < off) sred[tid] += sred[tid + off];
      __syncthreads();
    }
    if (tid == 0) pl_part[blockIdx.x * 4 + q] = sred[0];  // plain store
    __syncthreads();
  }

  // last-block epilogue
  __shared__ int s_last;
  __threadfence();
  if (tid == 0) {
    int old = atomicAdd(done_ctr, 1);
    s_last = (old == gridDim.x - 1) ? 1 : 0;
  }
  __syncthreads();
  if (!s_last) return;

  // device-scope atomic reads to dodge cross-XCD L2 staleness
  double a_bce = 0.0, a_norm = 0.0, a_x = 0.0, a_iou = 0.0, a_dfl = 0.0;
  for (int i = tid; i < PRE_GRID; i += 256) a_bce += atomicAdd(&bce_part[i], 0.0);
  for (int i = tid; i < PL_GRID; i += 256) {
    a_norm += atomicAdd(&pl_part[i * 4 + 0], 0.0);
    a_x    += atomicAdd(&pl_part[i * 4 + 1], 0.0);
    a_iou  += atomicAdd(&pl_part[i * 4 + 2], 0.0);
    a_dfl  += atomicAdd(&pl_part[i * 4 + 3], 0.0);
  }
  double acc5[5] = { a_bce, a_norm, a_x, a_iou, a_dfl };
  double tot5[5];
  for (int q = 0; q < 5; ++q) {
    sred[tid] = acc5[q];
    __syncthreads();
    for (int off = 128; off; off >>= 1) {
      if (tid < off) sred[tid] += sred[tid + off];
      __syncthreads();
    }
    tot5[q] = sred[0];
    __syncthreads();
  }
  if (tid == 0) {
    double tss = tot5[1]; if (tss < 1.0) tss = 1.0;
    double l0 = 0.5 * (tot5[0] - tot5[2]) / tss;
    double l1 = 7.5 * tot5[3] / tss;
    double l2 = 1.5 * tot5[4] / tss;
    out[0] = (float)(l0 + l1 + l2);
    out[1] = (float)l0;
    out[2] = (float)l1;
    out[3] = (float)l2;
  }
}

// ---------- launch ----------

extern "C" void kernel_launch(void* const* d_in, const int* in_sizes, int n_in,
                              void* d_out, int out_size, void* d_ws, size_t ws_size,
                              hipStream_t stream) {
  (void)in_sizes; (void)n_in; (void)out_size; (void)ws_size;
  const float* cls0  = (const float*)d_in[0];
  const float* cls1  = (const float*)d_in[1];
  const float* cls2  = (const float*)d_in[2];
  const float* reg0  = (const float*)d_in[3];
  const float* reg1  = (const float*)d_in[4];
  const float* reg2  = (const float*)d_in[5];
  const float* boxes = (const float*)d_in[6];
  const int*   labels = (const int*)d_in[7];
  float* out = (float*)d_out;

  const size_t BA = (size_t)NB * NA;  // 134400
  const int    BM = NB * NM;          // 512

  char* wsb = (char*)d_ws;
  double*   bce_part = (double*)wsb;                        // PRE_GRID
  double*   pl_part  = bce_part + PRE_GRID;                 // PL_GRID*4
  unsigned* pos_am   = (unsigned*)(pl_part + PL_GRID * 4);  // BM
  unsigned* pos_ov   = pos_am + BM;                         // BM
  int*      done_ctr = (int*)(pos_ov + BM);                 // 1 (+pad)
  int*      fgcnt    = done_ctr + 4;                        // BA
  int*      msum     = fgcnt + BA;                          // BA
  float*    bbp      = (float*)(msum + BA);                 // BA*4
  float*    mlsp     = bbp + BA * 4;                        // BA*4
  float*    amv      = mlsp + BA * 4;                       // BA
  int*      assign   = (int*)(amv + BA);                    // BA

  float4* bb  = (float4*)bbp;
  float4* mls = (float4*)mlsp;

  k_pre<<<PRE_GRID, 256, 0, stream>>>(reg0, reg1, reg2, cls0, cls1, cls2,
                                      bb, mls, fgcnt, msum, pos_am, pos_ov,
                                      done_ctr, bce_part);
  k_assign<<<BM, 256, 0, stream>>>(boxes, labels, (const float4*)bb,
                                   cls0, cls1, cls2, fgcnt, msum);
  k_resolve<<<PL_GRID, 256, 0, stream>>>(boxes, labels, (const float4*)bb, cls0, cls1, cls2,
                                         fgcnt, msum, assign, amv, pos_am, pos_ov);
  k_post<<<PL_GRID, 256, 0, stream>>>(cls0, cls1, cls2, reg0, reg1, reg2,
                                      boxes, labels, assign, amv,
                                      (const float4*)bb, (const float4*)mls, pos_am, pos_ov,
                                      pl_part, bce_part, done_ctr, out);
}

// Round 8
// 72.429 us; speedup vs baseline: 6.5684x; 1.3845x over previous
//
#include <hip/hip_runtime.h>

#define NB 16
#define NM 32
#define NA 8400
#define NCC 80
#define NREG 64
#define A0 6400
#define A1 1600
#define A2 400
#define CAP 768

#define PRE_GRID 1024
#define PL_GRID 525   // 525*256 == NB*NA

// acc: 4 padded fp64 slots (atomicAdd targets), 128B apart
// slot 0=tss 1=pos_cls 2=iou 3=dfl
#define ACC_STRIDE 16
#define ACC_SLOTS 4

// ---------- device helpers ----------

__device__ __forceinline__ void anch(int a, float& ax, float& ay, float& s, int& lvl, int& p) {
  if (a < A0)            { lvl = 0; p = a;          s = 8.f;  ax = (float)(p % 80); ay = (float)(p / 80); }
  else if (a < A0 + A1)  { lvl = 1; p = a - A0;     s = 16.f; ax = (float)(p % 40); ay = (float)(p / 40); }
  else                   { lvl = 2; p = a - A0 - A1; s = 32.f; ax = (float)(p % 20); ay = (float)(p / 20); }
}

__device__ __forceinline__ float cls_at(const float* c0, const float* c1, const float* c2,
                                        int b, int ch, int a) {
  if (a < A0)           return c0[((size_t)(b * NCC + ch)) * A0 + a];
  if (a < A0 + A1)      return c1[((size_t)(b * NCC + ch)) * A1 + (a - A0)];
  return c2[((size_t)(b * NCC + ch)) * A2 + (a - A0 - A1)];
}

__device__ __forceinline__ float reg_at(const float* r0, const float* r1, const float* r2,
                                        int b, int ch, int lvl, int p) {
  if (lvl == 0) return r0[((size_t)(b * NREG + ch)) * A0 + p];
  if (lvl == 1) return r1[((size_t)(b * NREG + ch)) * A1 + p];
  return r2[((size_t)(b * NREG + ch)) * A2 + p];
}

__device__ __forceinline__ void gtbox(const float* boxes, int b, int m,
                                      float& x1, float& y1, float& x2, float& y2, bool& valid) {
  const float* q = boxes + ((size_t)(b * NM + m)) * 4;
  float cx = q[0], cy = q[1], w = q[2], h = q[3];
  x1 = (cx - w * 0.5f) * 640.f; y1 = (cy - h * 0.5f) * 640.f;
  x2 = (cx + w * 0.5f) * 640.f; y2 = (cy + h * 0.5f) * 640.f;
  valid = (x1 + y1 + x2 + y2) > 0.f;
}

__device__ __forceinline__ float ciou_f(float b1x1, float b1y1, float b1x2, float b1y2,
                                        float b2x1, float b2y1, float b2x2, float b2y2) {
  const float eps = 1e-7f;
  float w1 = b1x2 - b1x1, h1 = b1y2 - b1y1;
  float w2 = b2x2 - b2x1, h2 = b2y2 - b2y1;
  float iw = fmaxf(fminf(b1x2, b2x2) - fmaxf(b1x1, b2x1), 0.f);
  float ih = fmaxf(fminf(b1y2, b2y2) - fmaxf(b1y1, b2y1), 0.f);
  float inter = iw * ih;
  float uni = w1 * h1 + w2 * h2 - inter + eps;
  float iou = inter / uni;
  float cw = fmaxf(b1x2, b2x2) - fminf(b1x1, b2x1);
  float ch = fmaxf(b1y2, b2y2) - fminf(b1y1, b2y1);
  float c2 = cw * cw + ch * ch + eps;
  float dx = b2x1 + b2x2 - b1x1 - b1x2;
  float dy = b2y1 + b2y2 - b1y1 - b1y2;
  float rho2 = (dx * dx + dy * dy) * 0.25f;
  float at = atanf(w2 / (h2 + eps)) - atanf(w1 / (h1 + eps));
  float v = 0.4052847345693511f * at * at;   // 4/pi^2
  float alpha = v / (v - iou + (1.0f + eps));
  return iou - (rho2 / c2 + v * alpha);
}

__device__ __forceinline__ float align_of(float sc, float o) {
  float o2 = o * o, o4 = o2 * o2;
  return sqrtf(sc) * (o2 * o4);  // sc^0.5 * o^6
}

__device__ __forceinline__ float softplus_fast(float x) {
  float e = __expf(-fabsf(x));
  return fmaxf(x, 0.f) + __logf(1.f + e);
}

// ---------- kernel 1: zero scratch + DFL decode + BCE softplus partials ----------

__global__ __launch_bounds__(256) void k_pre(
    const float* r0, const float* r1, const float* r2,
    const float* c0, const float* c1, const float* c2,
    float4* bb, float4* mls, int* fgcnt, int* msum,
    unsigned* pos_am, unsigned* pos_ov, double* acc, double* bce_part) {
  const int gtid = blockIdx.x * 256 + threadIdx.x;
  const int nthr = gridDim.x * 256;

  for (int t = gtid; t < NB * NA; t += nthr) {
    fgcnt[t] = 0; msum[t] = 0;
    if (t < NB * NM) { pos_am[t] = 0u; pos_ov[t] = 0u; }
    if (t < ACC_SLOTS * ACC_STRIDE) acc[t] = 0.0;   // only k_post writes acc (later dispatch)

    int b = t / NA, a = t % NA;
    float ax, ay, s; int lvl, p;
    anch(a, ax, ay, s, lvl, p);
    const float* rg; int HW;
    if (lvl == 0) { rg = r0; HW = A0; }
    else if (lvl == 1) { rg = r1; HW = A1; }
    else { rg = r2; HW = A2; }
    const float* base = rg + ((size_t)b * NREG) * HW + p;
    float dist[4], ml[4];
    for (int sd = 0; sd < 4; ++sd) {
      float x[16]; float mx = -1e30f;
      for (int r = 0; r < 16; ++r) { x[r] = base[(size_t)(sd * 16 + r) * HW]; mx = fmaxf(mx, x[r]); }
      float se = 0.f, wsum = 0.f;
      for (int r = 0; r < 16; ++r) { float e = __expf(x[r] - mx); se += e; wsum += e * (float)r; }
      dist[sd] = wsum / se;
      ml[sd] = mx + __logf(se);
    }
    bb[t]  = make_float4(ax - dist[0], ay - dist[1], ax + dist[2], ay + dist[3]);
    mls[t] = make_float4(ml[0], ml[1], ml[2], ml[3]);
  }

  // BCE softplus over all class logits (float4)
  const size_t N0 = (size_t)NB * NCC * A0 / 4;
  const size_t N1 = (size_t)NB * NCC * A1 / 4;
  const size_t N2 = (size_t)NB * NCC * A2 / 4;
  const size_t NT = N0 + N1 + N2;
  const float4* f0 = (const float4*)c0;
  const float4* f1 = (const float4*)c1;
  const float4* f2 = (const float4*)c2;
  float s0 = 0.f, s1 = 0.f;
  for (size_t i = (size_t)gtid; i < NT; i += (size_t)nthr) {
    float4 v;
    if (i < N0) v = f0[i];
    else if (i < N0 + N1) v = f1[i - N0];
    else v = f2[i - N0 - N1];
    s0 += softplus_fast(v.x) + softplus_fast(v.z);
    s1 += softplus_fast(v.y) + softplus_fast(v.w);
  }
  __shared__ double sred[256];
  sred[threadIdx.x] = (double)(s0 + s1);
  __syncthreads();
  for (int off = 128; off; off >>= 1) {
    if (threadIdx.x < off) sred[threadIdx.x] += sred[threadIdx.x + off];
    __syncthreads();
  }
  if (threadIdx.x == 0) bce_part[blockIdx.x] = sred[0];  // plain store; read next dispatch
}

// ---------- kernel 2: rect-scan candidates + in-block top-10 (exact lax.top_k ties) ----------

__global__ __launch_bounds__(256) void k_assign(
    const float* boxes, const int* labels, const float4* bb,
    const float* c0, const float* c1, const float* c2,
    int* fgcnt, int* msum) {
  __shared__ float sv[CAP];
  __shared__ int   si[CAP];
  __shared__ int   s_n;
  __shared__ float swv[4];
  __shared__ int   swi[4];
  __shared__ int   scnt[4];
  const int bm = blockIdx.x;
  const int b = bm / NM, m = bm % NM;
  const int tid = threadIdx.x;
  const int lane = tid & 63;
  const int wid = tid >> 6;

  float gx1, gy1, gx2, gy2; bool valid;
  gtbox(boxes, b, m, gx1, gy1, gx2, gy2, valid);
  if (!valid) return;   // uniform per block
  int lbl = labels[bm]; if (lbl < 0) lbl = 0; if (lbl >= NCC) lbl = NCC - 1;
  if (tid == 0) s_n = 0;
  __syncthreads();

  const int   Ws[3]   = {80, 40, 20};
  const float ss[3]   = {8.f, 16.f, 32.f};
  const int   loff[3] = {0, A0, A0 + A1};
  int rx0[3], ry0[3], rw[3], bc[3];
  int total = 0;
  for (int l = 0; l < 3; ++l) {
    float s = ss[l]; int W = Ws[l];
    int ax0 = (int)floorf((gx1 + 1e-9f) / s);
    int ax1 = (int)ceilf((gx2 - 1e-9f) / s);
    int ay0 = (int)floorf((gy1 + 1e-9f) / s);
    int ay1 = (int)ceilf((gy2 - 1e-9f) / s);
    ax0 = max(ax0, 0); ay0 = max(ay0, 0);
    ax1 = min(ax1, W - 1); ay1 = min(ay1, W - 1);
    rx0[l] = ax0; ry0[l] = ay0;
    rw[l] = max(0, ax1 - ax0 + 1);
    int rhl = max(0, ay1 - ay0 + 1);
    bc[l] = total;
    total += rw[l] * rhl;
  }
  int iters = (total + 255) >> 8;
  for (int it = 0; it < iters; ++it) {
    int idx = it * 256 + tid;
    bool pred = false; float am = 0.f; int a = 0;
    if (idx < total) {
      int l = (idx >= bc[2]) ? 2 : ((idx >= bc[1]) ? 1 : 0);
      int r = idx - bc[l];
      int iy = r / rw[l], ix = r - iy * rw[l];
      int axg = rx0[l] + ix, ayg = ry0[l] + iy;
      a = loff[l] + ayg * Ws[l] + axg;
      float s = ss[l];
      float axp = (float)axg * s, ayp = (float)ayg * s;
      float mn = fminf(fminf(axp - gx1, ayp - gy1), fminf(gx2 - axp, gy2 - ayp));
      if (mn > 1e-9f) {
        pred = true;
        float4 pb = bb[(size_t)b * NA + a];
        float c = ciou_f(gx1, gy1, gx2, gy2, pb.x * s, pb.y * s, pb.z * s, pb.w * s);
        float o = fmaxf(c, 0.f);
        float x = cls_at(c0, c1, c2, b, lbl, a);
        float sc = 1.f / (1.f + expf(-x));
        am = align_of(sc, o);
      }
    }
    unsigned long long mask = __ballot(pred);
    if (mask) {
      int nact = __popcll(mask);
      int leader = __ffsll(mask) - 1;
      int basec = 0;
      if (lane == leader) basec = atomicAdd(&s_n, nact);
      basec = __shfl(basec, leader);
      if (pred) {
        int off = basec + __popcll(mask & ((1ull << lane) - 1ull));
        if (off < CAP) { sv[off] = am; si[off] = a; }
      }
    }
  }
  __syncthreads();
  int n = s_n; if (n > CAP) n = CAP;
  if (n == 0) return;

  // count positives
  int cnt = 0;
  for (int j = tid; j < n; j += 256) if (sv[j] > 0.f) cnt++;
  for (int o = 32; o; o >>= 1) cnt += __shfl_xor(cnt, o);
  if (lane == 0) scnt[wid] = cnt;
  __syncthreads();
  if (tid == 0) scnt[0] = scnt[0] + scnt[1] + scnt[2] + scnt[3];
  __syncthreads();
  int npos = scnt[0];
  __syncthreads();

  if (npos > 10) {
    for (int k = 0; k < 10; ++k) {
      float bv = -1.f; int bi = 1 << 30;
      for (int j = tid; j < n; j += 256) {
        float v = sv[j]; int ix = si[j];
        if (v > bv || (v == bv && ix < bi)) { bv = v; bi = ix; }
      }
      for (int o = 32; o; o >>= 1) {
        float v = __shfl_xor(bv, o); int ix = __shfl_xor(bi, o);
        if (v > bv || (v == bv && ix < bi)) { bv = v; bi = ix; }
      }
      if (lane == 0) { swv[wid] = bv; swi[wid] = bi; }
      __syncthreads();
      if (tid == 0) {
        float v = swv[0]; int i = swi[0];
        for (int w = 1; w < 4; ++w)
          if (swv[w] > v || (swv[w] == v && swi[w] < i)) { v = swv[w]; i = swi[w]; }
        swi[0] = i;
      }
      __syncthreads();
      bi = swi[0];
      for (int j = tid; j < n; j += 256) if (si[j] == bi) sv[j] = -1.f;
      if (tid == 0) {
        atomicAdd(&fgcnt[(size_t)b * NA + bi], 1);
        atomicAdd(&msum[(size_t)b * NA + bi], m);
      }
      __syncthreads();
    }
  } else {
    for (int j = tid; j < n; j += 256) {
      if (sv[j] > 0.f) {
        atomicAdd(&fgcnt[(size_t)b * NA + si[j]], 1);
        atomicAdd(&msum[(size_t)b * NA + si[j]], m);
      }
    }
    // zero-tie fill (anchor index < 10 — rare corner)
    int need = 10 - npos;
    for (int j = tid; j < n; j += 256) {
      if (sv[j] == 0.f) {
        int i = si[j];
        if (i < 10) {
          int pb = 0;
          for (int q = 0; q < n; ++q) pb += (sv[q] > 0.f && si[q] < i) ? 1 : 0;
          if (i - pb < need) {
            atomicAdd(&fgcnt[(size_t)b * NA + i], 1);
            atomicAdd(&msum[(size_t)b * NA + i], m);
          }
        }
      }
    }
  }
}

// ---------- kernel 3: resolve assignment + per-gt maxima ----------

__global__ __launch_bounds__(256) void k_resolve(const float* boxes, const int* labels,
                                                 const float4* bb,
                                                 const float* c0, const float* c1, const float* c2,
                                                 const int* fgcnt, const int* msum,
                                                 int* assign, float* amv,
                                                 unsigned* pos_am, unsigned* pos_ov) {
  int t = blockIdx.x * blockDim.x + threadIdx.x;
  if (t >= NB * NA) return;
  int b = t / NA, a = t % NA;
  int fg = fgcnt[t];
  int asn = -1; float o = 0.f;
  if (fg > 0) {
    float ax, ay, s; int lvl, p;
    anch(a, ax, ay, s, lvl, p);
    float axp = ax * s, ayp = ay * s;
    float4 pb = bb[t];
    float px1 = pb.x * s, py1 = pb.y * s, px2 = pb.z * s, py2 = pb.w * s;
    if (fg == 1) {
      asn = msum[t];
      float gx1, gy1, gx2, gy2; bool valid;
      gtbox(boxes, b, asn, gx1, gy1, gx2, gy2, valid);
      o = fmaxf(ciou_f(gx1, gy1, gx2, gy2, px1, py1, px2, py2), 0.f);
    } else {
      float bv = -1e30f; int bi = 0;
      for (int m = 0; m < NM; ++m) {
        float gx1, gy1, gx2, gy2; bool valid;
        gtbox(boxes, b, m, gx1, gy1, gx2, gy2, valid);
        float om = 0.f;
        if (valid) {
          float mn = fminf(fminf(axp - gx1, ayp - gy1), fminf(gx2 - axp, gy2 - ayp));
          if (mn > 1e-9f)
            om = fmaxf(ciou_f(gx1, gy1, gx2, gy2, px1, py1, px2, py2), 0.f);
        }
        if (om > bv) { bv = om; bi = m; }
      }
      asn = bi; o = bv;
    }
    float am = 0.f;
    if (o > 0.f) {
      int lbl = labels[b * NM + asn]; if (lbl < 0) lbl = 0; if (lbl >= NCC) lbl = NCC - 1;
      float x = cls_at(c0, c1, c2, b, lbl, a);
      float sc = 1.f / (1.f + expf(-x));
      am = align_of(sc, o);
      atomicMax(&pos_am[b * NM + asn], __float_as_uint(am));
      atomicMax(&pos_ov[b * NM + asn], __float_as_uint(o));
    }
    amv[t] = am;
  }
  assign[t] = asn;
}

// ---------- kernel 4: pos losses -> block-reduced, 4 padded-slot atomics ----------

__global__ __launch_bounds__(256) void k_post(const float* c0, const float* c1, const float* c2,
    const float* r0, const float* r1, const float* r2,
    const float* boxes, const int* labels, const int* assign, const float* amv,
    const float4* bb, const float4* mls, const unsigned* pos_am, const unsigned* pos_ov,
    double* acc) {
  const int tid = threadIdx.x;
  const int t = blockIdx.x * 256 + tid;
  double t_norm = 0.0, t_x = 0.0, t_iou = 0.0, t_dfl = 0.0;
  int asn = (t < NB * NA) ? assign[t] : -1;
  if (asn >= 0) {
    int b = t / NA, a = t % NA;
    float pam = __uint_as_float(pos_am[b * NM + asn]);
    float pov = __uint_as_float(pos_ov[b * NM + asn]);
    float norm = amv[t] * pov / (pam + 1e-9f);
    int lbl = labels[b * NM + asn]; if (lbl < 0) lbl = 0; if (lbl >= NCC) lbl = NCC - 1;
    float x = cls_at(c0, c1, c2, b, lbl, a);
    float gx1, gy1, gx2, gy2; bool valid;
    gtbox(boxes, b, asn, gx1, gy1, gx2, gy2, valid);
    float ax, ay, s; int lvl, p;
    anch(a, ax, ay, s, lvl, p);
    float inv_s = 1.f / s;
    float tx1 = gx1 * inv_s, ty1 = gy1 * inv_s, tx2 = gx2 * inv_s, ty2 = gy2 * inv_s;
    float4 pb = bb[t];
    float iou = ciou_f(pb.x, pb.y, pb.z, pb.w, tx1, ty1, tx2, ty2);
    float4 ml = mls[t];
    float tgt[4] = { ax - tx1, ay - ty1, tx2 - ax, ty2 - ay };
    float mlv[4] = { ml.x, ml.y, ml.z, ml.w };
    float dfl = 0.f;
    for (int sd = 0; sd < 4; ++sd) {
      float tv = fminf(fmaxf(tgt[sd], 0.f), 14.99f);
      float tlf = floorf(tv);
      int tl = (int)tlf;
      float wl = (tlf + 1.f) - tv;
      float xtl = reg_at(r0, r1, r2, b, sd * 16 + tl,     lvl, p);
      float xtr = reg_at(r0, r1, r2, b, sd * 16 + tl + 1, lvl, p);
      dfl += -((xtl - mlv[sd]) * wl + (xtr - mlv[sd]) * (1.f - wl));
    }
    dfl *= 0.25f;
    t_norm = (double)norm;
    t_x    = (double)(norm * x);
    t_iou  = (double)((1.f - iou) * norm);
    t_dfl  = (double)(dfl * norm);
  }
  __shared__ double sred[256];
  double vals[4] = { t_norm, t_x, t_iou, t_dfl };
  for (int q = 0; q < 4; ++q) {
    sred[tid] = vals[q];
    __syncthreads();
    for (int off = 128; off; off >>= 1) {
      if (tid < off) sred[tid] += sred[tid + off];
      __syncthreads();
    }
    if (tid == 0 && sred[0] != 0.0) atomicAdd(&acc[q * ACC_STRIDE], sred[0]);
    __syncthreads();
  }
}

// ---------- kernel 5: sum BCE partials + compose outputs ----------

__global__ __launch_bounds__(256) void k_final(const double* bce_part, const double* acc, float* out) {
  __shared__ double sred[256];
  double s = 0.0;
  for (int i = threadIdx.x; i < PRE_GRID; i += 256) s += bce_part[i];
  sred[threadIdx.x] = s;
  __syncthreads();
  for (int off = 128; off; off >>= 1) {
    if (threadIdx.x < off) sred[threadIdx.x] += sred[threadIdx.x + off];
    __syncthreads();
  }
  if (threadIdx.x == 0) {
    double a_bce  = sred[0];
    double a_norm = acc[0 * ACC_STRIDE];
    double a_x    = acc[1 * ACC_STRIDE];
    double a_iou  = acc[2 * ACC_STRIDE];
    double a_dfl  = acc[3 * ACC_STRIDE];
    double tss = a_norm; if (tss < 1.0) tss = 1.0;
    double l0 = 0.5 * (a_bce - a_x) / tss;
    double l1 = 7.5 * a_iou / tss;
    double l2 = 1.5 * a_dfl / tss;
    out[0] = (float)(l0 + l1 + l2);
    out[1] = (float)l0;
    out[2] = (float)l1;
    out[3] = (float)l2;
  }
}

// ---------- launch ----------

extern "C" void kernel_launch(void* const* d_in, const int* in_sizes, int n_in,
                              void* d_out, int out_size, void* d_ws, size_t ws_size,
                              hipStream_t stream) {
  (void)in_sizes; (void)n_in; (void)out_size; (void)ws_size;
  const float* cls0  = (const float*)d_in[0];
  const float* cls1  = (const float*)d_in[1];
  const float* cls2  = (const float*)d_in[2];
  const float* reg0  = (const float*)d_in[3];
  const float* reg1  = (const float*)d_in[4];
  const float* reg2  = (const float*)d_in[5];
  const float* boxes = (const float*)d_in[6];
  const int*   labels = (const int*)d_in[7];
  float* out = (float*)d_out;

  const size_t BA = (size_t)NB * NA;  // 134400
  const int    BM = NB * NM;          // 512

  char* wsb = (char*)d_ws;
  double*   bce_part = (double*)wsb;                        // PRE_GRID
  double*   acc      = bce_part + PRE_GRID;                 // ACC_SLOTS*ACC_STRIDE
  unsigned* pos_am   = (unsigned*)(acc + ACC_SLOTS * ACC_STRIDE); // BM
  unsigned* pos_ov   = pos_am + BM;                         // BM
  int*      fgcnt    = (int*)(pos_ov + BM);                 // BA
  int*      msum     = fgcnt + BA;                          // BA
  float*    bbp      = (float*)(msum + BA);                 // BA*4
  float*    mlsp     = bbp + BA * 4;                        // BA*4
  float*    amv      = mlsp + BA * 4;                       // BA
  int*      assign   = (int*)(amv + BA);                    // BA

  float4* bb  = (float4*)bbp;
  float4* mls = (float4*)mlsp;

  k_pre<<<PRE_GRID, 256, 0, stream>>>(reg0, reg1, reg2, cls0, cls1, cls2,
                                      bb, mls, fgcnt, msum, pos_am, pos_ov,
                                      acc, bce_part);
  k_assign<<<BM, 256, 0, stream>>>(boxes, labels, (const float4*)bb,
                                   cls0, cls1, cls2, fgcnt, msum);
  k_resolve<<<PL_GRID, 256, 0, stream>>>(boxes, labels, (const float4*)bb, cls0, cls1, cls2,
                                         fgcnt, msum, assign, amv, pos_am, pos_ov);
  k_post<<<PL_GRID, 256, 0, stream>>>(cls0, cls1, cls2, reg0, reg1, reg2,
                                      boxes, labels, assign, amv,
                                      (const float4*)bb, (const float4*)mls, pos_am, pos_ov,
                                      acc);
  k_final<<<1, 256, 0, stream>>>(bce_part, acc, out);
}

// Round 9
// 67.688 us; speedup vs baseline: 7.0284x; 1.0700x over previous
//
#include <hip/hip_runtime.h>

#define NB 16
#define NM 32
#define NA 8400
#define NCC 80
#define NREG 64
#define A0 6400
#define A1 1600
#define A2 400
#define CAP 768

#define PRE_GRID 1024
#define PL_GRID 525   // 525*256 == NB*NA

// acc: 4 padded fp64 slots (atomicAdd targets), 128B apart
// slot 0=tss 1=pos_cls 2=iou 3=dfl
#define ACC_STRIDE 16
#define ACC_SLOTS 4

// ---------- device helpers ----------

__device__ __forceinline__ void anch(int a, float& ax, float& ay, float& s, int& lvl, int& p) {
  if (a < A0)            { lvl = 0; p = a;          s = 8.f;  ax = (float)(p % 80); ay = (float)(p / 80); }
  else if (a < A0 + A1)  { lvl = 1; p = a - A0;     s = 16.f; ax = (float)(p % 40); ay = (float)(p / 40); }
  else                   { lvl = 2; p = a - A0 - A1; s = 32.f; ax = (float)(p % 20); ay = (float)(p / 20); }
}

__device__ __forceinline__ float cls_at(const float* c0, const float* c1, const float* c2,
                                        int b, int ch, int a) {
  if (a < A0)           return c0[((size_t)(b * NCC + ch)) * A0 + a];
  if (a < A0 + A1)      return c1[((size_t)(b * NCC + ch)) * A1 + (a - A0)];
  return c2[((size_t)(b * NCC + ch)) * A2 + (a - A0 - A1)];
}

__device__ __forceinline__ float reg_at(const float* r0, const float* r1, const float* r2,
                                        int b, int ch, int lvl, int p) {
  if (lvl == 0) return r0[((size_t)(b * NREG + ch)) * A0 + p];
  if (lvl == 1) return r1[((size_t)(b * NREG + ch)) * A1 + p];
  return r2[((size_t)(b * NREG + ch)) * A2 + p];
}

__device__ __forceinline__ void gtbox(const float* boxes, int b, int m,
                                      float& x1, float& y1, float& x2, float& y2, bool& valid) {
  const float* q = boxes + ((size_t)(b * NM + m)) * 4;
  float cx = q[0], cy = q[1], w = q[2], h = q[3];
  x1 = (cx - w * 0.5f) * 640.f; y1 = (cy - h * 0.5f) * 640.f;
  x2 = (cx + w * 0.5f) * 640.f; y2 = (cy + h * 0.5f) * 640.f;
  valid = (x1 + y1 + x2 + y2) > 0.f;
}

__device__ __forceinline__ float ciou_f(float b1x1, float b1y1, float b1x2, float b1y2,
                                        float b2x1, float b2y1, float b2x2, float b2y2) {
  const float eps = 1e-7f;
  float w1 = b1x2 - b1x1, h1 = b1y2 - b1y1;
  float w2 = b2x2 - b2x1, h2 = b2y2 - b2y1;
  float iw = fmaxf(fminf(b1x2, b2x2) - fmaxf(b1x1, b2x1), 0.f);
  float ih = fmaxf(fminf(b1y2, b2y2) - fmaxf(b1y1, b2y1), 0.f);
  float inter = iw * ih;
  float uni = w1 * h1 + w2 * h2 - inter + eps;
  float iou = inter / uni;
  float cw = fmaxf(b1x2, b2x2) - fminf(b1x1, b2x1);
  float ch = fmaxf(b1y2, b2y2) - fminf(b1y1, b2y1);
  float c2 = cw * cw + ch * ch + eps;
  float dx = b2x1 + b2x2 - b1x1 - b1x2;
  float dy = b2y1 + b2y2 - b1y1 - b1y2;
  float rho2 = (dx * dx + dy * dy) * 0.25f;
  float at = atanf(w2 / (h2 + eps)) - atanf(w1 / (h1 + eps));
  float v = 0.4052847345693511f * at * at;   // 4/pi^2
  float alpha = v / (v - iou + (1.0f + eps));
  return iou - (rho2 / c2 + v * alpha);
}

__device__ __forceinline__ float align_of(float sc, float o) {
  float o2 = o * o, o4 = o2 * o2;
  return sqrtf(sc) * (o2 * o4);  // sc^0.5 * o^6
}

__device__ __forceinline__ float softplus_fast(float x) {
  float e = __expf(-fabsf(x));
  return fmaxf(x, 0.f) + __logf(1.f + e);
}

// ---------- kernel 1: zero scratch + DFL decode + BCE softplus partials ----------

__global__ __launch_bounds__(256) void k_pre(
    const float* r0, const float* r1, const float* r2,
    const float* c0, const float* c1, const float* c2,
    float4* bb, float4* mls, int* fgcnt, int* msum,
    unsigned* pos_am, unsigned* pos_ov, double* acc, double* bce_part) {
  const int gtid = blockIdx.x * 256 + threadIdx.x;
  const int nthr = gridDim.x * 256;

  for (int t = gtid; t < NB * NA; t += nthr) {
    fgcnt[t] = 0; msum[t] = 0;
    if (t < NB * NM) { pos_am[t] = 0u; pos_ov[t] = 0u; }
    if (t < ACC_SLOTS * ACC_STRIDE) acc[t] = 0.0;   // only k_post writes acc (later dispatch)

    int b = t / NA, a = t % NA;
    float ax, ay, s; int lvl, p;
    anch(a, ax, ay, s, lvl, p);
    const float* rg; int HW;
    if (lvl == 0) { rg = r0; HW = A0; }
    else if (lvl == 1) { rg = r1; HW = A1; }
    else { rg = r2; HW = A2; }
    const float* base = rg + ((size_t)b * NREG) * HW + p;
    float dist[4], ml[4];
    for (int sd = 0; sd < 4; ++sd) {
      float x[16]; float mx = -1e30f;
      for (int r = 0; r < 16; ++r) { x[r] = base[(size_t)(sd * 16 + r) * HW]; mx = fmaxf(mx, x[r]); }
      float se = 0.f, wsum = 0.f;
      for (int r = 0; r < 16; ++r) { float e = __expf(x[r] - mx); se += e; wsum += e * (float)r; }
      dist[sd] = wsum / se;
      ml[sd] = mx + __logf(se);
    }
    bb[t]  = make_float4(ax - dist[0], ay - dist[1], ax + dist[2], ay + dist[3]);
    mls[t] = make_float4(ml[0], ml[1], ml[2], ml[3]);
  }

  // BCE softplus over all class logits (float4)
  const size_t N0 = (size_t)NB * NCC * A0 / 4;
  const size_t N1 = (size_t)NB * NCC * A1 / 4;
  const size_t N2 = (size_t)NB * NCC * A2 / 4;
  const size_t NT = N0 + N1 + N2;
  const float4* f0 = (const float4*)c0;
  const float4* f1 = (const float4*)c1;
  const float4* f2 = (const float4*)c2;
  float s0 = 0.f, s1 = 0.f;
  for (size_t i = (size_t)gtid; i < NT; i += (size_t)nthr) {
    float4 v;
    if (i < N0) v = f0[i];
    else if (i < N0 + N1) v = f1[i - N0];
    else v = f2[i - N0 - N1];
    s0 += softplus_fast(v.x) + softplus_fast(v.z);
    s1 += softplus_fast(v.y) + softplus_fast(v.w);
  }
  __shared__ double sred[256];
  sred[threadIdx.x] = (double)(s0 + s1);
  __syncthreads();
  for (int off = 128; off; off >>= 1) {
    if (threadIdx.x < off) sred[threadIdx.x] += sred[threadIdx.x + off];
    __syncthreads();
  }
  if (threadIdx.x == 0) bce_part[blockIdx.x] = sred[0];  // plain store; read next dispatch
}

// ---------- kernel 2: rect-scan candidates + wave-local register top-10 ----------

__global__ __launch_bounds__(256) void k_assign(
    const float* boxes, const int* labels, const float4* bb,
    const float* c0, const float* c1, const float* c2,
    int* fgcnt, int* msum) {
  __shared__ float sv[CAP];
  __shared__ int   si[CAP];
  __shared__ int   s_n;
  const int bm = blockIdx.x;
  const int b = bm / NM, m = bm % NM;
  const int tid = threadIdx.x;
  const int lane = tid & 63;

  float gx1, gy1, gx2, gy2; bool valid;
  gtbox(boxes, b, m, gx1, gy1, gx2, gy2, valid);
  if (!valid) return;   // uniform per block
  int lbl = labels[bm]; if (lbl < 0) lbl = 0; if (lbl >= NCC) lbl = NCC - 1;
  if (tid == 0) s_n = 0;
  __syncthreads();

  const int   Ws[3]   = {80, 40, 20};
  const float ss[3]   = {8.f, 16.f, 32.f};
  const int   loff[3] = {0, A0, A0 + A1};
  int rx0[3], ry0[3], rw[3], bc[3];
  int total = 0;
  for (int l = 0; l < 3; ++l) {
    float s = ss[l]; int W = Ws[l];
    int ax0 = (int)floorf((gx1 + 1e-9f) / s);
    int ax1 = (int)ceilf((gx2 - 1e-9f) / s);
    int ay0 = (int)floorf((gy1 + 1e-9f) / s);
    int ay1 = (int)ceilf((gy2 - 1e-9f) / s);
    ax0 = max(ax0, 0); ay0 = max(ay0, 0);
    ax1 = min(ax1, W - 1); ay1 = min(ay1, W - 1);
    rx0[l] = ax0; ry0[l] = ay0;
    rw[l] = max(0, ax1 - ax0 + 1);
    int rhl = max(0, ay1 - ay0 + 1);
    bc[l] = total;
    total += rw[l] * rhl;
  }
  int iters = (total + 255) >> 8;
  for (int it = 0; it < iters; ++it) {
    int idx = it * 256 + tid;
    bool pred = false; float am = 0.f; int a = 0;
    if (idx < total) {
      int l = (idx >= bc[2]) ? 2 : ((idx >= bc[1]) ? 1 : 0);
      int r = idx - bc[l];
      int iy = r / rw[l], ix = r - iy * rw[l];
      int axg = rx0[l] + ix, ayg = ry0[l] + iy;
      a = loff[l] + ayg * Ws[l] + axg;
      float s = ss[l];
      float axp = (float)axg * s, ayp = (float)ayg * s;
      float mn = fminf(fminf(axp - gx1, ayp - gy1), fminf(gx2 - axp, gy2 - ayp));
      if (mn > 1e-9f) {
        pred = true;
        float4 pb = bb[(size_t)b * NA + a];
        float c = ciou_f(gx1, gy1, gx2, gy2, pb.x * s, pb.y * s, pb.z * s, pb.w * s);
        float o = fmaxf(c, 0.f);
        float x = cls_at(c0, c1, c2, b, lbl, a);
        float sc = 1.f / (1.f + expf(-x));
        am = align_of(sc, o);
      }
    }
    unsigned long long mask = __ballot(pred);
    if (mask) {
      int nact = __popcll(mask);
      int leader = __ffsll(mask) - 1;
      int basec = 0;
      if (lane == leader) basec = atomicAdd(&s_n, nact);
      basec = __shfl(basec, leader);
      if (pred) {
        int off = basec + __popcll(mask & ((1ull << lane) - 1ull));
        if (off < CAP) { sv[off] = am; si[off] = a; }
      }
    }
  }
  __syncthreads();
  int n = s_n; if (n > CAP) n = CAP;
  if (n == 0) return;
  if (tid >= 64) return;           // selection: wave 0 only, wave-synchronous

  // load candidates into registers: 12 slots/lane (CAP = 12*64)
  float v[12]; int ix[12];
#pragma unroll
  for (int k = 0; k < 12; ++k) {
    int j = k * 64 + tid;
    bool in = (j < n);
    v[k]  = in ? sv[j] : -2.f;
    ix[k] = in ? si[j] : (1 << 30);
  }
  // count positives (wave butterfly)
  int cnt = 0;
#pragma unroll
  for (int k = 0; k < 12; ++k) cnt += (v[k] > 0.f) ? 1 : 0;
  for (int o = 32; o; o >>= 1) cnt += __shfl_xor(cnt, o);
  int npos = cnt;

  if (npos > 10) {
    for (int p = 0; p < 10; ++p) {
      float bv = -1.f; int bi = 1 << 30;
#pragma unroll
      for (int k = 0; k < 12; ++k) {
        if (v[k] > bv || (v[k] == bv && ix[k] < bi)) { bv = v[k]; bi = ix[k]; }
      }
      for (int o = 32; o; o >>= 1) {
        float wv = __shfl_xor(bv, o); int wi = __shfl_xor(bi, o);
        if (wv > bv || (wv == bv && wi < bi)) { bv = wv; bi = wi; }
      }
#pragma unroll
      for (int k = 0; k < 12; ++k) if (ix[k] == bi) v[k] = -1.f;
      if (tid == 0) {
        atomicAdd(&fgcnt[(size_t)b * NA + bi], 1);
        atomicAdd(&msum[(size_t)b * NA + bi], m);
      }
    }
  } else {
    // all positive candidates are picked
#pragma unroll
    for (int k = 0; k < 12; ++k) {
      if (v[k] > 0.f) {
        atomicAdd(&fgcnt[(size_t)b * NA + ix[k]], 1);
        atomicAdd(&msum[(size_t)b * NA + ix[k]], m);
      }
    }
    // zero-tie fill (anchor index < 10 — rare corner); sv/si in LDS are unmodified here
    int need = 10 - npos;
    for (int j = tid; j < n; j += 64) {
      if (sv[j] == 0.f) {
        int i = si[j];
        if (i < 10) {
          int pb = 0;
          for (int q = 0; q < n; ++q) pb += (sv[q] > 0.f && si[q] < i) ? 1 : 0;
          if (i - pb < need) {
            atomicAdd(&fgcnt[(size_t)b * NA + i], 1);
            atomicAdd(&msum[(size_t)b * NA + i], m);
          }
        }
      }
    }
  }
}

// ---------- kernel 3: resolve assignment + per-gt maxima ----------

__global__ __launch_bounds__(256) void k_resolve(const float* boxes, const int* labels,
                                                 const float4* bb,
                                                 const float* c0, const float* c1, const float* c2,
                                                 const int* fgcnt, const int* msum,
                                                 int* assign, float* amv,
                                                 unsigned* pos_am, unsigned* pos_ov) {
  int t = blockIdx.x * blockDim.x + threadIdx.x;
  if (t >= NB * NA) return;
  int b = t / NA, a = t % NA;
  int fg = fgcnt[t];
  int asn = -1; float o = 0.f;
  if (fg > 0) {
    float ax, ay, s; int lvl, p;
    anch(a, ax, ay, s, lvl, p);
    float axp = ax * s, ayp = ay * s;
    float4 pb = bb[t];
    float px1 = pb.x * s, py1 = pb.y * s, px2 = pb.z * s, py2 = pb.w * s;
    if (fg == 1) {
      asn = msum[t];
      float gx1, gy1, gx2, gy2; bool valid;
      gtbox(boxes, b, asn, gx1, gy1, gx2, gy2, valid);
      o = fmaxf(ciou_f(gx1, gy1, gx2, gy2, px1, py1, px2, py2), 0.f);
    } else {
      float bv = -1e30f; int bi = 0;
      for (int m = 0; m < NM; ++m) {
        float gx1, gy1, gx2, gy2; bool valid;
        gtbox(boxes, b, m, gx1, gy1, gx2, gy2, valid);
        float om = 0.f;
        if (valid) {
          float mn = fminf(fminf(axp - gx1, ayp - gy1), fminf(gx2 - axp, gy2 - ayp));
          if (mn > 1e-9f)
            om = fmaxf(ciou_f(gx1, gy1, gx2, gy2, px1, py1, px2, py2), 0.f);
        }
        if (om > bv) { bv = om; bi = m; }
      }
      asn = bi; o = bv;
    }
    float am = 0.f;
    if (o > 0.f) {
      int lbl = labels[b * NM + asn]; if (lbl < 0) lbl = 0; if (lbl >= NCC) lbl = NCC - 1;
      float x = cls_at(c0, c1, c2, b, lbl, a);
      float sc = 1.f / (1.f + expf(-x));
      am = align_of(sc, o);
      atomicMax(&pos_am[b * NM + asn], __float_as_uint(am));
      atomicMax(&pos_ov[b * NM + asn], __float_as_uint(o));
    }
    amv[t] = am;
  }
  assign[t] = asn;
}

// ---------- kernel 4: pos losses -> block-reduced, 4 padded-slot atomics ----------

__global__ __launch_bounds__(256) void k_post(const float* c0, const float* c1, const float* c2,
    const float* r0, const float* r1, const float* r2,
    const float* boxes, const int* labels, const int* assign, const float* amv,
    const float4* bb, const float4* mls, const unsigned* pos_am, const unsigned* pos_ov,
    double* acc) {
  const int tid = threadIdx.x;
  const int t = blockIdx.x * 256 + tid;
  double t_norm = 0.0, t_x = 0.0, t_iou = 0.0, t_dfl = 0.0;
  int asn = (t < NB * NA) ? assign[t] : -1;
  if (asn >= 0) {
    int b = t / NA, a = t % NA;
    float pam = __uint_as_float(pos_am[b * NM + asn]);
    float pov = __uint_as_float(pos_ov[b * NM + asn]);
    float norm = amv[t] * pov / (pam + 1e-9f);
    int lbl = labels[b * NM + asn]; if (lbl < 0) lbl = 0; if (lbl >= NCC) lbl = NCC - 1;
    float x = cls_at(c0, c1, c2, b, lbl, a);
    float gx1, gy1, gx2, gy2; bool valid;
    gtbox(boxes, b, asn, gx1, gy1, gx2, gy2, valid);
    float ax, ay, s; int lvl, p;
    anch(a, ax, ay, s, lvl, p);
    float inv_s = 1.f / s;
    float tx1 = gx1 * inv_s, ty1 = gy1 * inv_s, tx2 = gx2 * inv_s, ty2 = gy2 * inv_s;
    float4 pb = bb[t];
    float iou = ciou_f(pb.x, pb.y, pb.z, pb.w, tx1, ty1, tx2, ty2);
    float4 ml = mls[t];
    float tgt[4] = { ax - tx1, ay - ty1, tx2 - ax, ty2 - ay };
    float mlv[4] = { ml.x, ml.y, ml.z, ml.w };
    float dfl = 0.f;
    for (int sd = 0; sd < 4; ++sd) {
      float tv = fminf(fmaxf(tgt[sd], 0.f), 14.99f);
      float tlf = floorf(tv);
      int tl = (int)tlf;
      float wl = (tlf + 1.f) - tv;
      float xtl = reg_at(r0, r1, r2, b, sd * 16 + tl,     lvl, p);
      float xtr = reg_at(r0, r1, r2, b, sd * 16 + tl + 1, lvl, p);
      dfl += -((xtl - mlv[sd]) * wl + (xtr - mlv[sd]) * (1.f - wl));
    }
    dfl *= 0.25f;
    t_norm = (double)norm;
    t_x    = (double)(norm * x);
    t_iou  = (double)((1.f - iou) * norm);
    t_dfl  = (double)(dfl * norm);
  }
  __shared__ double sred[256];
  double vals[4] = { t_norm, t_x, t_iou, t_dfl };
  for (int q = 0; q < 4; ++q) {
    sred[tid] = vals[q];
    __syncthreads();
    for (int off = 128; off; off >>= 1) {
      if (tid < off) sred[tid] += sred[tid + off];
      __syncthreads();
    }
    if (tid == 0 && sred[0] != 0.0) atomicAdd(&acc[q * ACC_STRIDE], sred[0]);
    __syncthreads();
  }
}

// ---------- kernel 5: sum BCE partials + compose outputs ----------

__global__ __launch_bounds__(256) void k_final(const double* bce_part, const double* acc, float* out) {
  __shared__ double sred[256];
  double s = 0.0;
  for (int i = threadIdx.x; i < PRE_GRID; i += 256) s += bce_part[i];
  sred[threadIdx.x] = s;
  __syncthreads();
  for (int off = 128; off; off >>= 1) {
    if (threadIdx.x < off) sred[threadIdx.x] += sred[threadIdx.x + off];
    __syncthreads();
  }
  if (threadIdx.x == 0) {
    double a_bce  = sred[0];
    double a_norm = acc[0 * ACC_STRIDE];
    double a_x    = acc[1 * ACC_STRIDE];
    double a_iou  = acc[2 * ACC_STRIDE];
    double a_dfl  = acc[3 * ACC_STRIDE];
    double tss = a_norm; if (tss < 1.0) tss = 1.0;
    double l0 = 0.5 * (a_bce - a_x) / tss;
    double l1 = 7.5 * a_iou / tss;
    double l2 = 1.5 * a_dfl / tss;
    out[0] = (float)(l0 + l1 + l2);
    out[1] = (float)l0;
    out[2] = (float)l1;
    out[3] = (float)l2;
  }
}

// ---------- launch ----------

extern "C" void kernel_launch(void* const* d_in, const int* in_sizes, int n_in,
                              void* d_out, int out_size, void* d_ws, size_t ws_size,
                              hipStream_t stream) {
  (void)in_sizes; (void)n_in; (void)out_size; (void)ws_size;
  const float* cls0  = (const float*)d_in[0];
  const float* cls1  = (const float*)d_in[1];
  const float* cls2  = (const float*)d_in[2];
  const float* reg0  = (const float*)d_in[3];
  const float* reg1  = (const float*)d_in[4];
  const float* reg2  = (const float*)d_in[5];
  const float* boxes = (const float*)d_in[6];
  const int*   labels = (const int*)d_in[7];
  float* out = (float*)d_out;

  const size_t BA = (size_t)NB * NA;  // 134400
  const int    BM = NB * NM;          // 512

  char* wsb = (char*)d_ws;
  double*   bce_part = (double*)wsb;                        // PRE_GRID
  double*   acc      = bce_part + PRE_GRID;                 // ACC_SLOTS*ACC_STRIDE
  unsigned* pos_am   = (unsigned*)(acc + ACC_SLOTS * ACC_STRIDE); // BM
  unsigned* pos_ov   = pos_am + BM;                         // BM
  int*      fgcnt    = (int*)(pos_ov + BM);                 // BA
  int*      msum     = fgcnt + BA;                          // BA
  float*    bbp      = (float*)(msum + BA);                 // BA*4
  float*    mlsp     = bbp + BA * 4;                        // BA*4
  float*    amv      = mlsp + BA * 4;                       // BA
  int*      assign   = (int*)(amv + BA);                    // BA

  float4* bb  = (float4*)bbp;
  float4* mls = (float4*)mlsp;

  k_pre<<<PRE_GRID, 256, 0, stream>>>(reg0, reg1, reg2, cls0, cls1, cls2,
                                      bb, mls, fgcnt, msum, pos_am, pos_ov,
                                      acc, bce_part);
  k_assign<<<BM, 256, 0, stream>>>(boxes, labels, (const float4*)bb,
                                   cls0, cls1, cls2, fgcnt, msum);
  k_resolve<<<PL_GRID, 256, 0, stream>>>(boxes, labels, (const float4*)bb, cls0, cls1, cls2,
                                         fgcnt, msum, assign, amv, pos_am, pos_ov);
  k_post<<<PL_GRID, 256, 0, stream>>>(cls0, cls1, cls2, reg0, reg1, reg2,
                                      boxes, labels, assign, amv,
                                      (const float4*)bb, (const float4*)mls, pos_am, pos_ov,
                                      acc);
  k_final<<<1, 256, 0, stream>>>(bce_part, acc, out);
}